// Round 13
// baseline (331.554 us; speedup 1.0000x reference)
//
#include <hip/hip_runtime.h>
#include <hip/hip_bf16.h>

// BiomarkerGNN: N=100000, E=1200000, F=128, HID=64, PROJ=32.
// Round 13: degree-sorted node processing for agg2. Packs of 4 nodes with
// near-equal degree (counting sort by degree, 64 bins) kill the
// max-vs-mean divergence waste (~23% of gather slots); inner gather step
// back to 4 (r10==r12 showed ILP depth 4 vs 8 is neutral). All per-node
// math identical to round 12 -> absmax unchanged.

#define HID 64

typedef unsigned short ushort_t;
typedef unsigned int uint_t;
typedef short bf16x8 __attribute__((ext_vector_type(8)));
typedef float f32x4 __attribute__((ext_vector_type(4)));

__device__ __forceinline__ float bflo(uint_t u) {
    union { unsigned u; float f; } c;
    c.u = u << 16;
    return c.f;
}
__device__ __forceinline__ float bfhi(uint_t u) {
    union { unsigned u; float f; } c;
    c.u = u & 0xFFFF0000u;
    return c.f;
}
__device__ __forceinline__ float bf2f(ushort_t u) {
    union { unsigned u; float f; } c;
    c.u = ((unsigned)u) << 16;
    return c.f;
}
__device__ __forceinline__ ushort_t f2bf(float f) {
    union { float f; unsigned u; } c;
    c.f = f;
    unsigned u = c.u;
    unsigned r = (u + 0x7FFFu + ((u >> 16) & 1u)) >> 16;  // RNE
    return (ushort_t)r;
}

__global__ __launch_bounds__(256) void deg_kernel(const int* __restrict__ dst, int E,
                                                  int* __restrict__ deg) {
    int e = blockIdx.x * 256 + threadIdx.x;
    if (e < E) atomicAdd(&deg[dst[e]], 1);
}

__global__ __launch_bounds__(256) void scanA(const int* __restrict__ deg,
                                             int* __restrict__ excl,
                                             int* __restrict__ partials, int N) {
    __shared__ int s[256];
    int t = threadIdx.x;
    int i = blockIdx.x * 256 + t;
    int v = (i < N) ? deg[i] : 0;
    s[t] = v;
    __syncthreads();
    for (int off = 1; off < 256; off <<= 1) {
        int u = (t >= off) ? s[t - off] : 0;
        __syncthreads();
        s[t] += u;
        __syncthreads();
    }
    if (i < N) excl[i] = s[t] - v;
    if (t == 255) partials[blockIdx.x] = s[255];
}

__global__ __launch_bounds__(512) void scanB(int* __restrict__ partials, int P) {
    __shared__ int s[512];
    int t = threadIdx.x;
    int v = (t < P) ? partials[t] : 0;
    s[t] = v;
    __syncthreads();
    for (int off = 1; off < 512; off <<= 1) {
        int u = (t >= off) ? s[t - off] : 0;
        __syncthreads();
        s[t] += u;
        __syncthreads();
    }
    if (t < P) partials[t] = s[t] - v;
}

__global__ __launch_bounds__(256) void scanC(const int* __restrict__ excl,
                                             const int* __restrict__ partials,
                                             const int* __restrict__ deg,
                                             int* __restrict__ row_start,
                                             int* __restrict__ cursor,
                                             float* __restrict__ dinv, int N, int E) {
    int i = blockIdx.x * 256 + threadIdx.x;
    if (i < N) {
        int rs = excl[i] + partials[blockIdx.x];
        row_start[i] = rs;
        cursor[i] = rs;
        dinv[i] = rsqrtf((float)deg[i] + 1.0f);
        if (i == 0) row_start[N] = E;
    }
}

// Range-partitioned CSR fill (round-9 write-combining fix).
__global__ __launch_bounds__(256) void fill_csr2(const int* __restrict__ src,
                                                 const int* __restrict__ dst, int E,
                                                 int* __restrict__ cursor,
                                                 int* __restrict__ csr_src, int N) {
    int rng = blockIdx.x & 7;
    int gr  = blockIdx.x >> 3;
    int lo = (int)(((long long)N * rng) >> 3);
    int hi = (int)(((long long)N * (rng + 1)) >> 3);
    int nthr = (gridDim.x >> 3) * 256;
    for (int e = gr * 256 + threadIdx.x; e < E; e += nthr) {
        int d = dst[e];
        if (d >= lo && d < hi) {
            int pos = atomicAdd(&cursor[d], 1);
            csr_src[pos] = src[e];
        }
    }
}

// ---- counting sort of nodes by degree (64 bins, deg clamped to 63) ----
__global__ __launch_bounds__(256) void sortA(const int* __restrict__ deg,
                                             int* __restrict__ bins, int N) {
    __shared__ int h[64];
    int t = threadIdx.x;
    if (t < 64) h[t] = 0;
    __syncthreads();
    int i = blockIdx.x * 256 + t;
    if (i < N) atomicAdd(&h[min(deg[i], 63)], 1);
    __syncthreads();
    if (t < 64 && h[t] > 0) atomicAdd(&bins[t], h[t]);
}

__global__ void sortB(int* __restrict__ bins) {  // 1 wave, 64 lanes
    int t = threadIdx.x;
    int orig = bins[t];
    int v = orig;
    for (int off = 1; off < 64; off <<= 1) {
        int u = __shfl_up(v, off, 64);
        if (t >= off) v += u;
    }
    bins[t] = v - orig;  // exclusive prefix -> becomes cursor
}

__global__ __launch_bounds__(256) void sortC(const int* __restrict__ deg,
                                             int* __restrict__ cursor64,
                                             int* __restrict__ perm, int N) {
    __shared__ int h[64];
    __shared__ int gbase[64];
    int t = threadIdx.x;
    if (t < 64) h[t] = 0;
    __syncthreads();
    int i = blockIdx.x * 256 + t;
    int d = 0, r = 0;
    bool ok = i < N;
    if (ok) {
        d = min(deg[i], 63);
        r = atomicAdd(&h[d], 1);  // LDS atomic: within-block-within-bin rank
    }
    __syncthreads();
    if (t < 64) gbase[t] = (h[t] > 0) ? atomicAdd(&cursor64[t], h[t]) : 0;
    __syncthreads();
    if (ok) perm[gbase[d] + r] = i;
}

// Convert W1/gW0 (128x64 f32) to fragment-ordered bf16 (B-frag layout).
__global__ __launch_bounds__(256) void prep_wfrag(const float* __restrict__ W1,
                                                  const float* __restrict__ gW0,
                                                  ushort_t* __restrict__ fW,
                                                  ushort_t* __restrict__ fG) {
    int i = blockIdx.x * 256 + threadIdx.x;
    if (i >= 16384) return;
    int w    = i >> 13;
    int j    = i & 8191;
    int e    = j & 7;
    int lane = (j >> 3) & 63;
    int nt   = (j >> 9) & 3;
    int kc   = (j >> 11) & 3;
    int k   = kc * 32 + (lane >> 4) * 8 + e;
    int col = nt * 16 + (lane & 15);
    const float* W = (w == 0) ? W1 : gW0;
    ushort_t v = f2bf(W[k * 64 + col]);
    if (w == 0) fW[j] = v; else fG[j] = v;
}

// MFMA row-GEMM (round 10, unchanged).
__global__ __launch_bounds__(256) void rowgemm_mfma(
    const float* __restrict__ x,
    const ushort_t* __restrict__ fW, const ushort_t* __restrict__ fG,
    const float* __restrict__ b1, const float* __restrict__ gamma,
    const float* __restrict__ beta, const float* __restrict__ rmean,
    const float* __restrict__ rvar, const float* __restrict__ dinv,
    ushort_t* __restrict__ h_mlp, ushort_t* __restrict__ hw_s, int N) {
    int tid = threadIdx.x, lane = tid & 63, wid = tid >> 6;
    int rb = (blockIdx.x * 4 + wid) * 16;
    if (rb >= N) return;
    int r0 = lane & 15, kg = lane >> 4;
    int arow = rb + r0;
    if (arow > N - 1) arow = N - 1;
    const float* xbase = x + (size_t)arow * 128 + kg * 8;

    f32x4 accA[4] = {{0,0,0,0},{0,0,0,0},{0,0,0,0},{0,0,0,0}};
    f32x4 accB[4] = {{0,0,0,0},{0,0,0,0},{0,0,0,0},{0,0,0,0}};

#pragma unroll
    for (int kc = 0; kc < 4; ++kc) {
        float4 xa = *(const float4*)(xbase + kc * 32);
        float4 xb = *(const float4*)(xbase + kc * 32 + 4);
        bf16x8 a;
        a[0] = (short)f2bf(xa.x); a[1] = (short)f2bf(xa.y);
        a[2] = (short)f2bf(xa.z); a[3] = (short)f2bf(xa.w);
        a[4] = (short)f2bf(xb.x); a[5] = (short)f2bf(xb.y);
        a[6] = (short)f2bf(xb.z); a[7] = (short)f2bf(xb.w);
#pragma unroll
        for (int nt = 0; nt < 4; ++nt) {
            bf16x8 bw = *(const bf16x8*)(fW + ((size_t)(kc * 4 + nt) * 64 + lane) * 8);
            bf16x8 bg = *(const bf16x8*)(fG + ((size_t)(kc * 4 + nt) * 64 + lane) * 8);
            accA[nt] = __builtin_amdgcn_mfma_f32_16x16x32_bf16(a, bw, accA[nt], 0, 0, 0);
            accB[nt] = __builtin_amdgcn_mfma_f32_16x16x32_bf16(a, bg, accB[nt], 0, 0, 0);
        }
    }

    float dv[4];
    bool okr[4];
#pragma unroll
    for (int rr = 0; rr < 4; ++rr) {
        int row = rb + kg * 4 + rr;
        okr[rr] = (row < N);
        dv[rr] = okr[rr] ? dinv[row] : 0.f;
    }
#pragma unroll
    for (int nt = 0; nt < 4; ++nt) {
        int col = nt * 16 + r0;
        float esc = gamma[col] * rsqrtf(rvar[col] + 1e-5f);
        float ebi = beta[col] + (b1[col] - rmean[col]) * esc;
#pragma unroll
        for (int rr = 0; rr < 4; ++rr) {
            int row = rb + kg * 4 + rr;
            if (okr[rr]) {
                float h = fmaxf(fmaf(accA[nt][rr], esc, ebi), 0.f);
                h_mlp[(size_t)row * HID + col] = f2bf(h);
                hw_s[(size_t)row * HID + col] = f2bf(accB[nt][rr] * dv[rr]);
            }
        }
    }
}

// Stage a 64x64 f32 weight into LDS transposed + XOR-swizzled.
__device__ __forceinline__ void stageWT(float* sWT, const float* W, int tid) {
    for (int i = tid; i < 4096; i += 256) {
        int k = i >> 6, c = i & 63;
        sWT[c * 64 + ((((k >> 2) ^ (c & 7)) << 2) | (k & 3))] = W[i];
    }
}

// 4 dst nodes per wave, processed in degree-sorted order via perm.
template <int MODE>
__global__ __launch_bounds__(256) void agg2(
    const ushort_t* __restrict__ hw_s, const int* __restrict__ row_start,
    const int* __restrict__ csr_src, const float* __restrict__ dinv,
    const int* __restrict__ perm,
    const float* __restrict__ gb,
    const float* __restrict__ Wn,
    const ushort_t* __restrict__ h_mlp,
    const float* __restrict__ gateW, const float* __restrict__ gateb,
    const float* __restrict__ pW1, const float* __restrict__ pb1,
    const float* __restrict__ pW2, const float* __restrict__ pb2,
    const float* __restrict__ cW, const float* __restrict__ cb,
    ushort_t* __restrict__ out_bf,
    float* __restrict__ logits, float* __restrict__ zproj, int N) {
    extern __shared__ float smem[];
    float* sWT  = smem;
    float* sW2T = smem + 4096;
    float* sbuf = smem + (MODE == 0 ? 4096 : 4096 + 2048);
    int tid = threadIdx.x, lane = tid & 63, wid = tid >> 6;
    float* shg = sbuf + wid * 256;

    if (MODE == 0) {
        stageWT(sWT, Wn, tid);
    } else {
        stageWT(sWT, pW1, tid);
        for (int i = tid; i < 2048; i += 256) {
            int k = i >> 5, c = i & 31;
            sW2T[c * 64 + ((((k >> 2) ^ (c & 7)) << 2) | (k & 3))] = pW2[i];
        }
    }
    __syncthreads();

    int g = lane >> 4, sub = lane & 15;
    float4 gb4 = ((const float4*)gb)[sub];
    float gWa = 0.f, gWb = 0.f, pb1v = 0.f, pb2v = 0.f, cWv = 0.f, gb0v = 0.f, cb0v = 0.f;
    if (MODE == 1) {
        gWa = gateW[lane];
        gWb = gateW[64 + lane];
        pb1v = pb1[lane];
        pb2v = pb2[lane & 31];
        cWv = cW[lane];
        gb0v = gateb[0];
        cb0v = cb[0];
    }

    int npacks = (N + 3) >> 2;
    for (int pack = blockIdx.x * 4 + wid; pack < npacks; pack += gridDim.x * 4) {
        int d0 = pack * 4;
        int li = d0 + g;                  // logical (sorted) index
        bool ok = li < N;
        int dd = perm[ok ? li : N - 1];   // physical node id
        int rs = row_start[dd];
        int deg = ok ? (row_start[dd + 1] - rs) : 0;

        uint2 sv = ((const uint2*)(hw_s + (size_t)dd * HID))[sub];
        float ax, ay, az, aw;
        if (ok) { ax = bflo(sv.x); ay = bfhi(sv.x); az = bflo(sv.y); aw = bfhi(sv.y); }
        else    { ax = ay = az = aw = 0.f; }

        int dmax = deg;
        dmax = max(dmax, __shfl_xor(dmax, 16, 64));
        dmax = max(dmax, __shfl_xor(dmax, 32, 64));

        for (int base = 0; base < dmax; base += 16) {
            int idx = (base + sub < deg) ? csr_src[rs + base + sub] : 0;
            int m = dmax - base;
            if (m > 16) m = 16;
            for (int j = 0; j < m; j += 4) {
                int s0 = __shfl(idx, (g << 4) | (j + 0), 64);
                int s1 = __shfl(idx, (g << 4) | (j + 1), 64);
                int s2 = __shfl(idx, (g << 4) | (j + 2), 64);
                int s3 = __shfl(idx, (g << 4) | (j + 3), 64);
                bool v0 = base + j + 0 < deg, v1 = base + j + 1 < deg;
                bool v2 = base + j + 2 < deg, v3 = base + j + 3 < deg;
                uint2 g0 = ((const uint2*)(hw_s + (size_t)s0 * HID))[sub];
                uint2 g1 = ((const uint2*)(hw_s + (size_t)s1 * HID))[sub];
                uint2 g2 = ((const uint2*)(hw_s + (size_t)s2 * HID))[sub];
                uint2 g3 = ((const uint2*)(hw_s + (size_t)s3 * HID))[sub];
                if (v0) { ax += bflo(g0.x); ay += bfhi(g0.x); az += bflo(g0.y); aw += bfhi(g0.y); }
                if (v1) { ax += bflo(g1.x); ay += bfhi(g1.x); az += bflo(g1.y); aw += bfhi(g1.y); }
                if (v2) { ax += bflo(g2.x); ay += bfhi(g2.x); az += bflo(g2.y); aw += bfhi(g2.y); }
                if (v3) { ax += bflo(g3.x); ay += bfhi(g3.x); az += bflo(g3.y); aw += bfhi(g3.y); }
            }
        }

        float dv = dinv[dd];
        float h0 = fmaxf(fmaf(ax, dv, gb4.x), 0.f);
        float h1 = fmaxf(fmaf(ay, dv, gb4.y), 0.f);
        float h2 = fmaxf(fmaf(az, dv, gb4.z), 0.f);
        float h3 = fmaxf(fmaf(aw, dv, gb4.w), 0.f);
        if (!ok) { h0 = h1 = h2 = h3 = 0.f; }
        *(float4*)&shg[g * 64 + 4 * sub] = make_float4(h0, h1, h2, h3);

        // physical node ids of the 4 groups (for scattered stores)
        int dd0 = __shfl(dd, 0, 64);
        int dd1 = __shfl(dd, 16, 64);
        int dd2 = __shfl(dd, 32, 64);
        int dd3 = __shfl(dd, 48, 64);

        if (MODE == 0) {
            float a0 = 0.f, a1 = 0.f, a2 = 0.f, a3 = 0.f;
#pragma unroll 4
            for (int kq = 0; kq < 16; ++kq) {
                float4 w4 = *(const float4*)&sWT[lane * 64 + ((kq ^ (lane & 7)) << 2)];
                float4 x0 = *(const float4*)&shg[0 * 64 + kq * 4];
                float4 x1 = *(const float4*)&shg[1 * 64 + kq * 4];
                float4 x2 = *(const float4*)&shg[2 * 64 + kq * 4];
                float4 x3 = *(const float4*)&shg[3 * 64 + kq * 4];
                a0 = fmaf(x0.x, w4.x, a0); a0 = fmaf(x0.y, w4.y, a0);
                a0 = fmaf(x0.z, w4.z, a0); a0 = fmaf(x0.w, w4.w, a0);
                a1 = fmaf(x1.x, w4.x, a1); a1 = fmaf(x1.y, w4.y, a1);
                a1 = fmaf(x1.z, w4.z, a1); a1 = fmaf(x1.w, w4.w, a1);
                a2 = fmaf(x2.x, w4.x, a2); a2 = fmaf(x2.y, w4.y, a2);
                a2 = fmaf(x2.z, w4.z, a2); a2 = fmaf(x2.w, w4.w, a2);
                a3 = fmaf(x3.x, w4.x, a3); a3 = fmaf(x3.y, w4.y, a3);
                a3 = fmaf(x3.z, w4.z, a3); a3 = fmaf(x3.w, w4.w, a3);
            }
            float dv0 = __shfl(dv, 0, 64);
            float dv1 = __shfl(dv, 16, 64);
            float dv2 = __shfl(dv, 32, 64);
            float dv3 = __shfl(dv, 48, 64);
            if (d0 + 0 < N) out_bf[(size_t)dd0 * HID + lane] = f2bf(a0 * dv0);
            if (d0 + 1 < N) out_bf[(size_t)dd1 * HID + lane] = f2bf(a1 * dv1);
            if (d0 + 2 < N) out_bf[(size_t)dd2 * HID + lane] = f2bf(a2 * dv2);
            if (d0 + 3 < N) out_bf[(size_t)dd3 * HID + lane] = f2bf(a3 * dv3);
        } else {
            float hm0 = (d0 + 0 < N) ? bf2f(h_mlp[(size_t)dd0 * HID + lane]) : 0.f;
            float hm1 = (d0 + 1 < N) ? bf2f(h_mlp[(size_t)dd1 * HID + lane]) : 0.f;
            float hm2 = (d0 + 2 < N) ? bf2f(h_mlp[(size_t)dd2 * HID + lane]) : 0.f;
            float hm3 = (d0 + 3 < N) ? bf2f(h_mlp[(size_t)dd3 * HID + lane]) : 0.f;
            float hg0 = shg[0 * 64 + lane];
            float hg1 = shg[1 * 64 + lane];
            float hg2 = shg[2 * 64 + lane];
            float hg3 = shg[3 * 64 + lane];
            float p0 = fmaf(hm0, gWa, hg0 * gWb);
            float p1 = fmaf(hm1, gWa, hg1 * gWb);
            float p2 = fmaf(hm2, gWa, hg2 * gWb);
            float p3 = fmaf(hm3, gWa, hg3 * gWb);
#pragma unroll
            for (int mm = 32; mm >= 1; mm >>= 1) {
                p0 += __shfl_xor(p0, mm, 64);
                p1 += __shfl_xor(p1, mm, 64);
                p2 += __shfl_xor(p2, mm, 64);
                p3 += __shfl_xor(p3, mm, 64);
            }
            float gate0 = 1.f / (1.f + expf(-(p0 + gb0v)));
            float gate1 = 1.f / (1.f + expf(-(p1 + gb0v)));
            float gate2 = 1.f / (1.f + expf(-(p2 + gb0v)));
            float gate3 = 1.f / (1.f + expf(-(p3 + gb0v)));
            float hf0 = gate0 * hg0 + (1.f - gate0) * hm0;
            float hf1 = gate1 * hg1 + (1.f - gate1) * hm1;
            float hf2 = gate2 * hg2 + (1.f - gate2) * hm2;
            float hf3 = gate3 * hg3 + (1.f - gate3) * hm3;
            shg[0 * 64 + lane] = hf0;
            shg[1 * 64 + lane] = hf1;
            shg[2 * 64 + lane] = hf2;
            shg[3 * 64 + lane] = hf3;
            float t0 = 0.f, t1 = 0.f, t2 = 0.f, t3 = 0.f;
#pragma unroll 4
            for (int kq = 0; kq < 16; ++kq) {
                float4 w4 = *(const float4*)&sWT[lane * 64 + ((kq ^ (lane & 7)) << 2)];
                float4 x0 = *(const float4*)&shg[0 * 64 + kq * 4];
                float4 x1 = *(const float4*)&shg[1 * 64 + kq * 4];
                float4 x2 = *(const float4*)&shg[2 * 64 + kq * 4];
                float4 x3 = *(const float4*)&shg[3 * 64 + kq * 4];
                t0 = fmaf(x0.x, w4.x, t0); t0 = fmaf(x0.y, w4.y, t0);
                t0 = fmaf(x0.z, w4.z, t0); t0 = fmaf(x0.w, w4.w, t0);
                t1 = fmaf(x1.x, w4.x, t1); t1 = fmaf(x1.y, w4.y, t1);
                t1 = fmaf(x1.z, w4.z, t1); t1 = fmaf(x1.w, w4.w, t1);
                t2 = fmaf(x2.x, w4.x, t2); t2 = fmaf(x2.y, w4.y, t2);
                t2 = fmaf(x2.z, w4.z, t2); t2 = fmaf(x2.w, w4.w, t2);
                t3 = fmaf(x3.x, w4.x, t3); t3 = fmaf(x3.y, w4.y, t3);
                t3 = fmaf(x3.z, w4.z, t3); t3 = fmaf(x3.w, w4.w, t3);
            }
            t0 = fmaxf(t0 + pb1v, 0.f);
            t1 = fmaxf(t1 + pb1v, 0.f);
            t2 = fmaxf(t2 + pb1v, 0.f);
            t3 = fmaxf(t3 + pb1v, 0.f);
            shg[0 * 64 + lane] = t0;
            shg[1 * 64 + lane] = t1;
            shg[2 * 64 + lane] = t2;
            shg[3 * 64 + lane] = t3;
            int c2 = lane & 31, hh = lane >> 5;
            float z0 = 0.f, z1 = 0.f, z2 = 0.f, z3 = 0.f;
#pragma unroll 4
            for (int kq8 = 0; kq8 < 8; ++kq8) {
                int kq = hh * 8 + kq8;
                float4 w4 = *(const float4*)&sW2T[c2 * 64 + ((kq ^ (c2 & 7)) << 2)];
                float4 x0 = *(const float4*)&shg[0 * 64 + kq * 4];
                float4 x1 = *(const float4*)&shg[1 * 64 + kq * 4];
                float4 x2 = *(const float4*)&shg[2 * 64 + kq * 4];
                float4 x3 = *(const float4*)&shg[3 * 64 + kq * 4];
                z0 = fmaf(x0.x, w4.x, z0); z0 = fmaf(x0.y, w4.y, z0);
                z0 = fmaf(x0.z, w4.z, z0); z0 = fmaf(x0.w, w4.w, z0);
                z1 = fmaf(x1.x, w4.x, z1); z1 = fmaf(x1.y, w4.y, z1);
                z1 = fmaf(x1.z, w4.z, z1); z1 = fmaf(x1.w, w4.w, z1);
                z2 = fmaf(x2.x, w4.x, z2); z2 = fmaf(x2.y, w4.y, z2);
                z2 = fmaf(x2.z, w4.z, z2); z2 = fmaf(x2.w, w4.w, z2);
                z3 = fmaf(x3.x, w4.x, z3); z3 = fmaf(x3.y, w4.y, z3);
                z3 = fmaf(x3.z, w4.z, z3); z3 = fmaf(x3.w, w4.w, z3);
            }
            z0 += __shfl_xor(z0, 32, 64);
            z1 += __shfl_xor(z1, 32, 64);
            z2 += __shfl_xor(z2, 32, 64);
            z3 += __shfl_xor(z3, 32, 64);
            if (lane < 32) {
                if (d0 + 0 < N) zproj[(size_t)dd0 * 32 + c2] = z0 + pb2v;
                if (d0 + 1 < N) zproj[(size_t)dd1 * 32 + c2] = z1 + pb2v;
                if (d0 + 2 < N) zproj[(size_t)dd2 * 32 + c2] = z2 + pb2v;
                if (d0 + 3 < N) zproj[(size_t)dd3 * 32 + c2] = z3 + pb2v;
            }
            float q0 = hf0 * cWv, q1 = hf1 * cWv, q2 = hf2 * cWv, q3 = hf3 * cWv;
#pragma unroll
            for (int mm = 32; mm >= 1; mm >>= 1) {
                q0 += __shfl_xor(q0, mm, 64);
                q1 += __shfl_xor(q1, mm, 64);
                q2 += __shfl_xor(q2, mm, 64);
                q3 += __shfl_xor(q3, mm, 64);
            }
            if (lane == 0) {
                if (d0 + 0 < N) logits[dd0] = q0 + cb0v;
                if (d0 + 1 < N) logits[dd1] = q1 + cb0v;
                if (d0 + 2 < N) logits[dd2] = q2 + cb0v;
                if (d0 + 3 < N) logits[dd3] = q3 + cb0v;
            }
        }
    }
}

extern "C" void kernel_launch(void* const* d_in, const int* in_sizes, int n_in,
                              void* d_out, int out_size, void* d_ws, size_t ws_size,
                              hipStream_t stream) {
    const float* x     = (const float*)d_in[0];
    const int*   edge  = (const int*)d_in[1];
    const float* W1    = (const float*)d_in[2];
    const float* b1    = (const float*)d_in[3];
    const float* gamma = (const float*)d_in[4];
    const float* beta  = (const float*)d_in[5];
    const float* rmean = (const float*)d_in[6];
    const float* rvar  = (const float*)d_in[7];
    const float* gW0   = (const float*)d_in[8];
    const float* gb0   = (const float*)d_in[9];
    const float* gW1   = (const float*)d_in[10];
    const float* gb1   = (const float*)d_in[11];
    const float* gW2   = (const float*)d_in[12];
    const float* gb2   = (const float*)d_in[13];
    const float* gateW = (const float*)d_in[14];
    const float* gateb = (const float*)d_in[15];
    const float* pW1   = (const float*)d_in[16];
    const float* pb1   = (const float*)d_in[17];
    const float* pW2   = (const float*)d_in[18];
    const float* pb2   = (const float*)d_in[19];
    const float* cW    = (const float*)d_in[20];
    const float* cb    = (const float*)d_in[21];

    const int N = in_sizes[0] / 128;
    const int E = in_sizes[1] / 2;
    const int* e_src = edge;
    const int* e_dst = edge + E;

    char* ws = (char*)d_ws;
    size_t o = 0;
    auto alloc = [&](size_t bytes) {
        void* p = ws + o;
        o += (bytes + 15) & ~(size_t)15;
        return p;
    };
    int* deg       = (int*)alloc((size_t)N * 4);
    int* excl      = (int*)alloc((size_t)N * 4);
    int* partials  = (int*)alloc(512 * 4);
    int* row_start = (int*)alloc(((size_t)N + 1) * 4);
    int* cursor    = (int*)alloc((size_t)N * 4);
    int* csr_src   = (int*)alloc((size_t)E * 4);
    float* dinv    = (float*)alloc((size_t)N * 4);
    int* bins      = (int*)alloc(64 * 4);
    int* perm      = (int*)alloc((size_t)N * 4);
    ushort_t* fW   = (ushort_t*)alloc(8192 * 2);
    ushort_t* fG   = (ushort_t*)alloc(8192 * 2);
    ushort_t* h_mlp= (ushort_t*)alloc((size_t)N * 64 * 2);
    ushort_t* hwA  = (ushort_t*)alloc((size_t)N * 64 * 2);
    ushort_t* hwB  = (ushort_t*)alloc((size_t)N * 64 * 2);

    float* logits = (float*)d_out;
    float* zproj  = (float*)d_out + N;

    const int nblkN = (N + 255) / 256;
    const int nblkE = (E + 255) / 256;
    const int nblkG = (N + 63) / 64;
    const int blk0  = 2048;
    const int blk1  = 1280;
    const size_t lds0 = (4096 + 4 * 256) * 4;             // 20 KB
    const size_t lds1 = (4096 + 2048 + 4 * 256) * 4;      // 28 KB

    hipMemsetAsync(deg, 0, (size_t)N * sizeof(int), stream);
    hipMemsetAsync(bins, 0, 64 * sizeof(int), stream);
    deg_kernel<<<nblkE, 256, 0, stream>>>(e_dst, E, deg);
    scanA<<<nblkN, 256, 0, stream>>>(deg, excl, partials, N);
    scanB<<<1, 512, 0, stream>>>(partials, nblkN);
    scanC<<<nblkN, 256, 0, stream>>>(excl, partials, deg, row_start, cursor, dinv, N, E);
    fill_csr2<<<2048, 256, 0, stream>>>(e_src, e_dst, E, cursor, csr_src, N);

    // degree-sorted node order
    sortA<<<nblkN, 256, 0, stream>>>(deg, bins, N);
    sortB<<<1, 64, 0, stream>>>(bins);
    sortC<<<nblkN, 256, 0, stream>>>(deg, bins, perm, N);

    prep_wfrag<<<64, 256, 0, stream>>>(W1, gW0, fW, fG);
    rowgemm_mfma<<<nblkG, 256, 0, stream>>>(x, fW, fG, b1, gamma, beta, rmean,
                                            rvar, dinv, h_mlp, hwA, N);

    agg2<0><<<blk0, 256, lds0, stream>>>(hwA, row_start, csr_src, dinv, perm, gb0,
                                         gW1, nullptr, nullptr, nullptr,
                                         nullptr, nullptr, nullptr, nullptr,
                                         nullptr, nullptr, hwB, nullptr, nullptr, N);
    agg2<0><<<blk0, 256, lds0, stream>>>(hwB, row_start, csr_src, dinv, perm, gb1,
                                         gW2, nullptr, nullptr, nullptr,
                                         nullptr, nullptr, nullptr, nullptr,
                                         nullptr, nullptr, hwA, nullptr, nullptr, N);
    agg2<1><<<blk1, 256, lds1, stream>>>(hwA, row_start, csr_src, dinv, perm, gb2,
                                         nullptr, h_mlp, gateW, gateb,
                                         pW1, pb1, pW2, pb2, cW, cb,
                                         nullptr, logits, zproj, N);
}

// Round 14
// 306.858 us; speedup vs baseline: 1.0805x; 1.0805x over previous
//
#include <hip/hip_runtime.h>
#include <hip/hip_bf16.h>

// BiomarkerGNN: N=100000, E=1200000, F=128, HID=64, PROJ=32.
// Round 14: REVERT to round-12 (best, 307us). Round-13's degree-sort
// regressed (+17% FETCH from perm-scattered access; sort overhead).
// agg2 is at the random-gather fabric wall: 5 independent levers all leave
// it at 77-88us with FETCH == compulsory volume.

#define HID 64

typedef unsigned short ushort_t;
typedef unsigned int uint_t;
typedef short bf16x8 __attribute__((ext_vector_type(8)));
typedef float f32x4 __attribute__((ext_vector_type(4)));

__device__ __forceinline__ float bflo(uint_t u) {
    union { unsigned u; float f; } c;
    c.u = u << 16;
    return c.f;
}
__device__ __forceinline__ float bfhi(uint_t u) {
    union { unsigned u; float f; } c;
    c.u = u & 0xFFFF0000u;
    return c.f;
}
__device__ __forceinline__ float bf2f(ushort_t u) {
    union { unsigned u; float f; } c;
    c.u = ((unsigned)u) << 16;
    return c.f;
}
__device__ __forceinline__ ushort_t f2bf(float f) {
    union { float f; unsigned u; } c;
    c.f = f;
    unsigned u = c.u;
    unsigned r = (u + 0x7FFFu + ((u >> 16) & 1u)) >> 16;  // RNE
    return (ushort_t)r;
}

__global__ __launch_bounds__(256) void deg_kernel(const int* __restrict__ dst, int E,
                                                  int* __restrict__ deg) {
    int e = blockIdx.x * 256 + threadIdx.x;
    if (e < E) atomicAdd(&deg[dst[e]], 1);
}

__global__ __launch_bounds__(256) void scanA(const int* __restrict__ deg,
                                             int* __restrict__ excl,
                                             int* __restrict__ partials, int N) {
    __shared__ int s[256];
    int t = threadIdx.x;
    int i = blockIdx.x * 256 + t;
    int v = (i < N) ? deg[i] : 0;
    s[t] = v;
    __syncthreads();
    for (int off = 1; off < 256; off <<= 1) {
        int u = (t >= off) ? s[t - off] : 0;
        __syncthreads();
        s[t] += u;
        __syncthreads();
    }
    if (i < N) excl[i] = s[t] - v;
    if (t == 255) partials[blockIdx.x] = s[255];
}

__global__ __launch_bounds__(512) void scanB(int* __restrict__ partials, int P) {
    __shared__ int s[512];
    int t = threadIdx.x;
    int v = (t < P) ? partials[t] : 0;
    s[t] = v;
    __syncthreads();
    for (int off = 1; off < 512; off <<= 1) {
        int u = (t >= off) ? s[t - off] : 0;
        __syncthreads();
        s[t] += u;
        __syncthreads();
    }
    if (t < P) partials[t] = s[t] - v;
}

__global__ __launch_bounds__(256) void scanC(const int* __restrict__ excl,
                                             const int* __restrict__ partials,
                                             const int* __restrict__ deg,
                                             int* __restrict__ row_start,
                                             int* __restrict__ cursor,
                                             float* __restrict__ dinv, int N, int E) {
    int i = blockIdx.x * 256 + threadIdx.x;
    if (i < N) {
        int rs = excl[i] + partials[blockIdx.x];
        row_start[i] = rs;
        cursor[i] = rs;
        dinv[i] = rsqrtf((float)deg[i] + 1.0f);
        if (i == 0) row_start[N] = E;
    }
}

// Range-partitioned CSR fill (round-9 write-combining fix).
__global__ __launch_bounds__(256) void fill_csr2(const int* __restrict__ src,
                                                 const int* __restrict__ dst, int E,
                                                 int* __restrict__ cursor,
                                                 int* __restrict__ csr_src, int N) {
    int rng = blockIdx.x & 7;
    int gr  = blockIdx.x >> 3;
    int lo = (int)(((long long)N * rng) >> 3);
    int hi = (int)(((long long)N * (rng + 1)) >> 3);
    int nthr = (gridDim.x >> 3) * 256;
    for (int e = gr * 256 + threadIdx.x; e < E; e += nthr) {
        int d = dst[e];
        if (d >= lo && d < hi) {
            int pos = atomicAdd(&cursor[d], 1);
            csr_src[pos] = src[e];
        }
    }
}

// Convert W1/gW0 (128x64 f32) to fragment-ordered bf16 (B-frag layout).
__global__ __launch_bounds__(256) void prep_wfrag(const float* __restrict__ W1,
                                                  const float* __restrict__ gW0,
                                                  ushort_t* __restrict__ fW,
                                                  ushort_t* __restrict__ fG) {
    int i = blockIdx.x * 256 + threadIdx.x;
    if (i >= 16384) return;
    int w    = i >> 13;
    int j    = i & 8191;
    int e    = j & 7;
    int lane = (j >> 3) & 63;
    int nt   = (j >> 9) & 3;
    int kc   = (j >> 11) & 3;
    int k   = kc * 32 + (lane >> 4) * 8 + e;
    int col = nt * 16 + (lane & 15);
    const float* W = (w == 0) ? W1 : gW0;
    ushort_t v = f2bf(W[k * 64 + col]);
    if (w == 0) fW[j] = v; else fG[j] = v;
}

// MFMA row-GEMM (round 10, unchanged).
__global__ __launch_bounds__(256) void rowgemm_mfma(
    const float* __restrict__ x,
    const ushort_t* __restrict__ fW, const ushort_t* __restrict__ fG,
    const float* __restrict__ b1, const float* __restrict__ gamma,
    const float* __restrict__ beta, const float* __restrict__ rmean,
    const float* __restrict__ rvar, const float* __restrict__ dinv,
    ushort_t* __restrict__ h_mlp, ushort_t* __restrict__ hw_s, int N) {
    int tid = threadIdx.x, lane = tid & 63, wid = tid >> 6;
    int rb = (blockIdx.x * 4 + wid) * 16;
    if (rb >= N) return;
    int r0 = lane & 15, kg = lane >> 4;
    int arow = rb + r0;
    if (arow > N - 1) arow = N - 1;
    const float* xbase = x + (size_t)arow * 128 + kg * 8;

    f32x4 accA[4] = {{0,0,0,0},{0,0,0,0},{0,0,0,0},{0,0,0,0}};
    f32x4 accB[4] = {{0,0,0,0},{0,0,0,0},{0,0,0,0},{0,0,0,0}};

#pragma unroll
    for (int kc = 0; kc < 4; ++kc) {
        float4 xa = *(const float4*)(xbase + kc * 32);
        float4 xb = *(const float4*)(xbase + kc * 32 + 4);
        bf16x8 a;
        a[0] = (short)f2bf(xa.x); a[1] = (short)f2bf(xa.y);
        a[2] = (short)f2bf(xa.z); a[3] = (short)f2bf(xa.w);
        a[4] = (short)f2bf(xb.x); a[5] = (short)f2bf(xb.y);
        a[6] = (short)f2bf(xb.z); a[7] = (short)f2bf(xb.w);
#pragma unroll
        for (int nt = 0; nt < 4; ++nt) {
            bf16x8 bw = *(const bf16x8*)(fW + ((size_t)(kc * 4 + nt) * 64 + lane) * 8);
            bf16x8 bg = *(const bf16x8*)(fG + ((size_t)(kc * 4 + nt) * 64 + lane) * 8);
            accA[nt] = __builtin_amdgcn_mfma_f32_16x16x32_bf16(a, bw, accA[nt], 0, 0, 0);
            accB[nt] = __builtin_amdgcn_mfma_f32_16x16x32_bf16(a, bg, accB[nt], 0, 0, 0);
        }
    }

    float dv[4];
    bool okr[4];
#pragma unroll
    for (int rr = 0; rr < 4; ++rr) {
        int row = rb + kg * 4 + rr;
        okr[rr] = (row < N);
        dv[rr] = okr[rr] ? dinv[row] : 0.f;
    }
#pragma unroll
    for (int nt = 0; nt < 4; ++nt) {
        int col = nt * 16 + r0;
        float esc = gamma[col] * rsqrtf(rvar[col] + 1e-5f);
        float ebi = beta[col] + (b1[col] - rmean[col]) * esc;
#pragma unroll
        for (int rr = 0; rr < 4; ++rr) {
            int row = rb + kg * 4 + rr;
            if (okr[rr]) {
                float h = fmaxf(fmaf(accA[nt][rr], esc, ebi), 0.f);
                h_mlp[(size_t)row * HID + col] = f2bf(h);
                hw_s[(size_t)row * HID + col] = f2bf(accB[nt][rr] * dv[rr]);
            }
        }
    }
}

// Stage a 64x64 f32 weight into LDS transposed + XOR-swizzled.
__device__ __forceinline__ void stageWT(float* sWT, const float* W, int tid) {
    for (int i = tid; i < 4096; i += 256) {
        int k = i >> 6, c = i & 63;
        sWT[c * 64 + ((((k >> 2) ^ (c & 7)) << 2) | (k & 3))] = W[i];
    }
}

// 4 dst nodes per wave; coalesced idx load + shfl broadcast, 8-deep ILP.
template <int MODE>
__global__ __launch_bounds__(256) void agg2(
    const ushort_t* __restrict__ hw_s, const int* __restrict__ row_start,
    const int* __restrict__ csr_src, const float* __restrict__ dinv,
    const float* __restrict__ gb,
    const float* __restrict__ Wn,
    const ushort_t* __restrict__ h_mlp,
    const float* __restrict__ gateW, const float* __restrict__ gateb,
    const float* __restrict__ pW1, const float* __restrict__ pb1,
    const float* __restrict__ pW2, const float* __restrict__ pb2,
    const float* __restrict__ cW, const float* __restrict__ cb,
    ushort_t* __restrict__ out_bf,
    float* __restrict__ logits, float* __restrict__ zproj, int N) {
    extern __shared__ float smem[];
    float* sWT  = smem;
    float* sW2T = smem + 4096;
    float* sbuf = smem + (MODE == 0 ? 4096 : 4096 + 2048);
    int tid = threadIdx.x, lane = tid & 63, wid = tid >> 6;
    float* shg = sbuf + wid * 256;

    if (MODE == 0) {
        stageWT(sWT, Wn, tid);
    } else {
        stageWT(sWT, pW1, tid);
        for (int i = tid; i < 2048; i += 256) {
            int k = i >> 5, c = i & 31;
            sW2T[c * 64 + ((((k >> 2) ^ (c & 7)) << 2) | (k & 3))] = pW2[i];
        }
    }
    __syncthreads();

    int g = lane >> 4, sub = lane & 15;
    float4 gb4 = ((const float4*)gb)[sub];
    float gWa = 0.f, gWb = 0.f, pb1v = 0.f, pb2v = 0.f, cWv = 0.f, gb0v = 0.f, cb0v = 0.f;
    if (MODE == 1) {
        gWa = gateW[lane];
        gWb = gateW[64 + lane];
        pb1v = pb1[lane];
        pb2v = pb2[lane & 31];
        cWv = cW[lane];
        gb0v = gateb[0];
        cb0v = cb[0];
    }

    int npacks = (N + 3) >> 2;
    for (int pack = blockIdx.x * 4 + wid; pack < npacks; pack += gridDim.x * 4) {
        int d0 = pack * 4;
        int d = d0 + g;
        bool ok = d < N;
        int dd = ok ? d : N - 1;
        int rs = row_start[dd];
        int deg = ok ? (row_start[dd + 1] - rs) : 0;

        uint2 sv = ((const uint2*)(hw_s + (size_t)dd * HID))[sub];
        float ax, ay, az, aw;
        if (ok) { ax = bflo(sv.x); ay = bfhi(sv.x); az = bflo(sv.y); aw = bfhi(sv.y); }
        else    { ax = ay = az = aw = 0.f; }

        int dmax = deg;
        dmax = max(dmax, __shfl_xor(dmax, 16, 64));
        dmax = max(dmax, __shfl_xor(dmax, 32, 64));

        for (int base = 0; base < dmax; base += 16) {
            int idx = (base + sub < deg) ? csr_src[rs + base + sub] : 0;
            int m = dmax - base;
            if (m > 16) m = 16;
            for (int j = 0; j < m; j += 8) {
                int s0 = __shfl(idx, (g << 4) | (j + 0), 64);
                int s1 = __shfl(idx, (g << 4) | (j + 1), 64);
                int s2 = __shfl(idx, (g << 4) | (j + 2), 64);
                int s3 = __shfl(idx, (g << 4) | (j + 3), 64);
                int s4 = __shfl(idx, (g << 4) | ((j + 4) & 15), 64);
                int s5 = __shfl(idx, (g << 4) | ((j + 5) & 15), 64);
                int s6 = __shfl(idx, (g << 4) | ((j + 6) & 15), 64);
                int s7 = __shfl(idx, (g << 4) | ((j + 7) & 15), 64);
                bool v0 = base + j + 0 < deg, v1 = base + j + 1 < deg;
                bool v2 = base + j + 2 < deg, v3 = base + j + 3 < deg;
                bool v4 = base + j + 4 < deg, v5 = base + j + 5 < deg;
                bool v6 = base + j + 6 < deg, v7 = base + j + 7 < deg;
                uint2 g0 = ((const uint2*)(hw_s + (size_t)s0 * HID))[sub];
                uint2 g1 = ((const uint2*)(hw_s + (size_t)s1 * HID))[sub];
                uint2 g2 = ((const uint2*)(hw_s + (size_t)s2 * HID))[sub];
                uint2 g3 = ((const uint2*)(hw_s + (size_t)s3 * HID))[sub];
                uint2 g4 = ((const uint2*)(hw_s + (size_t)s4 * HID))[sub];
                uint2 g5 = ((const uint2*)(hw_s + (size_t)s5 * HID))[sub];
                uint2 g6 = ((const uint2*)(hw_s + (size_t)s6 * HID))[sub];
                uint2 g7 = ((const uint2*)(hw_s + (size_t)s7 * HID))[sub];
                if (v0) { ax += bflo(g0.x); ay += bfhi(g0.x); az += bflo(g0.y); aw += bfhi(g0.y); }
                if (v1) { ax += bflo(g1.x); ay += bfhi(g1.x); az += bflo(g1.y); aw += bfhi(g1.y); }
                if (v2) { ax += bflo(g2.x); ay += bfhi(g2.x); az += bflo(g2.y); aw += bfhi(g2.y); }
                if (v3) { ax += bflo(g3.x); ay += bfhi(g3.x); az += bflo(g3.y); aw += bfhi(g3.y); }
                if (v4) { ax += bflo(g4.x); ay += bfhi(g4.x); az += bflo(g4.y); aw += bfhi(g4.y); }
                if (v5) { ax += bflo(g5.x); ay += bfhi(g5.x); az += bflo(g5.y); aw += bfhi(g5.y); }
                if (v6) { ax += bflo(g6.x); ay += bfhi(g6.x); az += bflo(g6.y); aw += bfhi(g6.y); }
                if (v7) { ax += bflo(g7.x); ay += bfhi(g7.x); az += bflo(g7.y); aw += bfhi(g7.y); }
            }
        }

        float dv = dinv[dd];
        float h0 = fmaxf(fmaf(ax, dv, gb4.x), 0.f);
        float h1 = fmaxf(fmaf(ay, dv, gb4.y), 0.f);
        float h2 = fmaxf(fmaf(az, dv, gb4.z), 0.f);
        float h3 = fmaxf(fmaf(aw, dv, gb4.w), 0.f);
        if (!ok) { h0 = h1 = h2 = h3 = 0.f; }
        *(float4*)&shg[g * 64 + 4 * sub] = make_float4(h0, h1, h2, h3);

        if (MODE == 0) {
            float a0 = 0.f, a1 = 0.f, a2 = 0.f, a3 = 0.f;
#pragma unroll 4
            for (int kq = 0; kq < 16; ++kq) {
                float4 w4 = *(const float4*)&sWT[lane * 64 + ((kq ^ (lane & 7)) << 2)];
                float4 x0 = *(const float4*)&shg[0 * 64 + kq * 4];
                float4 x1 = *(const float4*)&shg[1 * 64 + kq * 4];
                float4 x2 = *(const float4*)&shg[2 * 64 + kq * 4];
                float4 x3 = *(const float4*)&shg[3 * 64 + kq * 4];
                a0 = fmaf(x0.x, w4.x, a0); a0 = fmaf(x0.y, w4.y, a0);
                a0 = fmaf(x0.z, w4.z, a0); a0 = fmaf(x0.w, w4.w, a0);
                a1 = fmaf(x1.x, w4.x, a1); a1 = fmaf(x1.y, w4.y, a1);
                a1 = fmaf(x1.z, w4.z, a1); a1 = fmaf(x1.w, w4.w, a1);
                a2 = fmaf(x2.x, w4.x, a2); a2 = fmaf(x2.y, w4.y, a2);
                a2 = fmaf(x2.z, w4.z, a2); a2 = fmaf(x2.w, w4.w, a2);
                a3 = fmaf(x3.x, w4.x, a3); a3 = fmaf(x3.y, w4.y, a3);
                a3 = fmaf(x3.z, w4.z, a3); a3 = fmaf(x3.w, w4.w, a3);
            }
            float dv0 = __shfl(dv, 0, 64);
            float dv1 = __shfl(dv, 16, 64);
            float dv2 = __shfl(dv, 32, 64);
            float dv3 = __shfl(dv, 48, 64);
            if (d0 + 0 < N) out_bf[(size_t)(d0 + 0) * HID + lane] = f2bf(a0 * dv0);
            if (d0 + 1 < N) out_bf[(size_t)(d0 + 1) * HID + lane] = f2bf(a1 * dv1);
            if (d0 + 2 < N) out_bf[(size_t)(d0 + 2) * HID + lane] = f2bf(a2 * dv2);
            if (d0 + 3 < N) out_bf[(size_t)(d0 + 3) * HID + lane] = f2bf(a3 * dv3);
        } else {
            float hm0 = (d0 + 0 < N) ? bf2f(h_mlp[(size_t)(d0 + 0) * HID + lane]) : 0.f;
            float hm1 = (d0 + 1 < N) ? bf2f(h_mlp[(size_t)(d0 + 1) * HID + lane]) : 0.f;
            float hm2 = (d0 + 2 < N) ? bf2f(h_mlp[(size_t)(d0 + 2) * HID + lane]) : 0.f;
            float hm3 = (d0 + 3 < N) ? bf2f(h_mlp[(size_t)(d0 + 3) * HID + lane]) : 0.f;
            float hg0 = shg[0 * 64 + lane];
            float hg1 = shg[1 * 64 + lane];
            float hg2 = shg[2 * 64 + lane];
            float hg3 = shg[3 * 64 + lane];
            float p0 = fmaf(hm0, gWa, hg0 * gWb);
            float p1 = fmaf(hm1, gWa, hg1 * gWb);
            float p2 = fmaf(hm2, gWa, hg2 * gWb);
            float p3 = fmaf(hm3, gWa, hg3 * gWb);
#pragma unroll
            for (int mm = 32; mm >= 1; mm >>= 1) {
                p0 += __shfl_xor(p0, mm, 64);
                p1 += __shfl_xor(p1, mm, 64);
                p2 += __shfl_xor(p2, mm, 64);
                p3 += __shfl_xor(p3, mm, 64);
            }
            float gate0 = 1.f / (1.f + expf(-(p0 + gb0v)));
            float gate1 = 1.f / (1.f + expf(-(p1 + gb0v)));
            float gate2 = 1.f / (1.f + expf(-(p2 + gb0v)));
            float gate3 = 1.f / (1.f + expf(-(p3 + gb0v)));
            float hf0 = gate0 * hg0 + (1.f - gate0) * hm0;
            float hf1 = gate1 * hg1 + (1.f - gate1) * hm1;
            float hf2 = gate2 * hg2 + (1.f - gate2) * hm2;
            float hf3 = gate3 * hg3 + (1.f - gate3) * hm3;
            shg[0 * 64 + lane] = hf0;
            shg[1 * 64 + lane] = hf1;
            shg[2 * 64 + lane] = hf2;
            shg[3 * 64 + lane] = hf3;
            float t0 = 0.f, t1 = 0.f, t2 = 0.f, t3 = 0.f;
#pragma unroll 4
            for (int kq = 0; kq < 16; ++kq) {
                float4 w4 = *(const float4*)&sWT[lane * 64 + ((kq ^ (lane & 7)) << 2)];
                float4 x0 = *(const float4*)&shg[0 * 64 + kq * 4];
                float4 x1 = *(const float4*)&shg[1 * 64 + kq * 4];
                float4 x2 = *(const float4*)&shg[2 * 64 + kq * 4];
                float4 x3 = *(const float4*)&shg[3 * 64 + kq * 4];
                t0 = fmaf(x0.x, w4.x, t0); t0 = fmaf(x0.y, w4.y, t0);
                t0 = fmaf(x0.z, w4.z, t0); t0 = fmaf(x0.w, w4.w, t0);
                t1 = fmaf(x1.x, w4.x, t1); t1 = fmaf(x1.y, w4.y, t1);
                t1 = fmaf(x1.z, w4.z, t1); t1 = fmaf(x1.w, w4.w, t1);
                t2 = fmaf(x2.x, w4.x, t2); t2 = fmaf(x2.y, w4.y, t2);
                t2 = fmaf(x2.z, w4.z, t2); t2 = fmaf(x2.w, w4.w, t2);
                t3 = fmaf(x3.x, w4.x, t3); t3 = fmaf(x3.y, w4.y, t3);
                t3 = fmaf(x3.z, w4.z, t3); t3 = fmaf(x3.w, w4.w, t3);
            }
            t0 = fmaxf(t0 + pb1v, 0.f);
            t1 = fmaxf(t1 + pb1v, 0.f);
            t2 = fmaxf(t2 + pb1v, 0.f);
            t3 = fmaxf(t3 + pb1v, 0.f);
            shg[0 * 64 + lane] = t0;
            shg[1 * 64 + lane] = t1;
            shg[2 * 64 + lane] = t2;
            shg[3 * 64 + lane] = t3;
            int c2 = lane & 31, hh = lane >> 5;
            float z0 = 0.f, z1 = 0.f, z2 = 0.f, z3 = 0.f;
#pragma unroll 4
            for (int kq8 = 0; kq8 < 8; ++kq8) {
                int kq = hh * 8 + kq8;
                float4 w4 = *(const float4*)&sW2T[c2 * 64 + ((kq ^ (c2 & 7)) << 2)];
                float4 x0 = *(const float4*)&shg[0 * 64 + kq * 4];
                float4 x1 = *(const float4*)&shg[1 * 64 + kq * 4];
                float4 x2 = *(const float4*)&shg[2 * 64 + kq * 4];
                float4 x3 = *(const float4*)&shg[3 * 64 + kq * 4];
                z0 = fmaf(x0.x, w4.x, z0); z0 = fmaf(x0.y, w4.y, z0);
                z0 = fmaf(x0.z, w4.z, z0); z0 = fmaf(x0.w, w4.w, z0);
                z1 = fmaf(x1.x, w4.x, z1); z1 = fmaf(x1.y, w4.y, z1);
                z1 = fmaf(x1.z, w4.z, z1); z1 = fmaf(x1.w, w4.w, z1);
                z2 = fmaf(x2.x, w4.x, z2); z2 = fmaf(x2.y, w4.y, z2);
                z2 = fmaf(x2.z, w4.z, z2); z2 = fmaf(x2.w, w4.w, z2);
                z3 = fmaf(x3.x, w4.x, z3); z3 = fmaf(x3.y, w4.y, z3);
                z3 = fmaf(x3.z, w4.z, z3); z3 = fmaf(x3.w, w4.w, z3);
            }
            z0 += __shfl_xor(z0, 32, 64);
            z1 += __shfl_xor(z1, 32, 64);
            z2 += __shfl_xor(z2, 32, 64);
            z3 += __shfl_xor(z3, 32, 64);
            if (lane < 32) {
                if (d0 + 0 < N) zproj[(size_t)(d0 + 0) * 32 + c2] = z0 + pb2v;
                if (d0 + 1 < N) zproj[(size_t)(d0 + 1) * 32 + c2] = z1 + pb2v;
                if (d0 + 2 < N) zproj[(size_t)(d0 + 2) * 32 + c2] = z2 + pb2v;
                if (d0 + 3 < N) zproj[(size_t)(d0 + 3) * 32 + c2] = z3 + pb2v;
            }
            float q0 = hf0 * cWv, q1 = hf1 * cWv, q2 = hf2 * cWv, q3 = hf3 * cWv;
#pragma unroll
            for (int mm = 32; mm >= 1; mm >>= 1) {
                q0 += __shfl_xor(q0, mm, 64);
                q1 += __shfl_xor(q1, mm, 64);
                q2 += __shfl_xor(q2, mm, 64);
                q3 += __shfl_xor(q3, mm, 64);
            }
            if (lane == 0) {
                if (d0 + 0 < N) logits[d0 + 0] = q0 + cb0v;
                if (d0 + 1 < N) logits[d0 + 1] = q1 + cb0v;
                if (d0 + 2 < N) logits[d0 + 2] = q2 + cb0v;
                if (d0 + 3 < N) logits[d0 + 3] = q3 + cb0v;
            }
        }
    }
}

extern "C" void kernel_launch(void* const* d_in, const int* in_sizes, int n_in,
                              void* d_out, int out_size, void* d_ws, size_t ws_size,
                              hipStream_t stream) {
    const float* x     = (const float*)d_in[0];
    const int*   edge  = (const int*)d_in[1];
    const float* W1    = (const float*)d_in[2];
    const float* b1    = (const float*)d_in[3];
    const float* gamma = (const float*)d_in[4];
    const float* beta  = (const float*)d_in[5];
    const float* rmean = (const float*)d_in[6];
    const float* rvar  = (const float*)d_in[7];
    const float* gW0   = (const float*)d_in[8];
    const float* gb0   = (const float*)d_in[9];
    const float* gW1   = (const float*)d_in[10];
    const float* gb1   = (const float*)d_in[11];
    const float* gW2   = (const float*)d_in[12];
    const float* gb2   = (const float*)d_in[13];
    const float* gateW = (const float*)d_in[14];
    const float* gateb = (const float*)d_in[15];
    const float* pW1   = (const float*)d_in[16];
    const float* pb1   = (const float*)d_in[17];
    const float* pW2   = (const float*)d_in[18];
    const float* pb2   = (const float*)d_in[19];
    const float* cW    = (const float*)d_in[20];
    const float* cb    = (const float*)d_in[21];

    const int N = in_sizes[0] / 128;
    const int E = in_sizes[1] / 2;
    const int* e_src = edge;
    const int* e_dst = edge + E;

    char* ws = (char*)d_ws;
    size_t o = 0;
    auto alloc = [&](size_t bytes) {
        void* p = ws + o;
        o += (bytes + 15) & ~(size_t)15;
        return p;
    };
    int* deg       = (int*)alloc((size_t)N * 4);
    int* excl      = (int*)alloc((size_t)N * 4);
    int* partials  = (int*)alloc(512 * 4);
    int* row_start = (int*)alloc(((size_t)N + 1) * 4);
    int* cursor    = (int*)alloc((size_t)N * 4);
    int* csr_src   = (int*)alloc((size_t)E * 4);
    float* dinv    = (float*)alloc((size_t)N * 4);
    ushort_t* fW   = (ushort_t*)alloc(8192 * 2);
    ushort_t* fG   = (ushort_t*)alloc(8192 * 2);
    ushort_t* h_mlp= (ushort_t*)alloc((size_t)N * 64 * 2);
    ushort_t* hwA  = (ushort_t*)alloc((size_t)N * 64 * 2);
    ushort_t* hwB  = (ushort_t*)alloc((size_t)N * 64 * 2);

    float* logits = (float*)d_out;
    float* zproj  = (float*)d_out + N;

    const int nblkN = (N + 255) / 256;
    const int nblkE = (E + 255) / 256;
    const int nblkG = (N + 63) / 64;
    const int blk0  = 2048;
    const int blk1  = 1280;
    const size_t lds0 = (4096 + 4 * 256) * 4;             // 20 KB
    const size_t lds1 = (4096 + 2048 + 4 * 256) * 4;      // 28 KB

    hipMemsetAsync(deg, 0, (size_t)N * sizeof(int), stream);
    deg_kernel<<<nblkE, 256, 0, stream>>>(e_dst, E, deg);
    scanA<<<nblkN, 256, 0, stream>>>(deg, excl, partials, N);
    scanB<<<1, 512, 0, stream>>>(partials, nblkN);
    scanC<<<nblkN, 256, 0, stream>>>(excl, partials, deg, row_start, cursor, dinv, N, E);
    fill_csr2<<<2048, 256, 0, stream>>>(e_src, e_dst, E, cursor, csr_src, N);

    prep_wfrag<<<64, 256, 0, stream>>>(W1, gW0, fW, fG);
    rowgemm_mfma<<<nblkG, 256, 0, stream>>>(x, fW, fG, b1, gamma, beta, rmean,
                                            rvar, dinv, h_mlp, hwA, N);

    agg2<0><<<blk0, 256, lds0, stream>>>(hwA, row_start, csr_src, dinv, gb0,
                                         gW1, nullptr, nullptr, nullptr,
                                         nullptr, nullptr, nullptr, nullptr,
                                         nullptr, nullptr, hwB, nullptr, nullptr, N);
    agg2<0><<<blk0, 256, lds0, stream>>>(hwB, row_start, csr_src, dinv, gb1,
                                         gW2, nullptr, nullptr, nullptr,
                                         nullptr, nullptr, nullptr, nullptr,
                                         nullptr, nullptr, hwA, nullptr, nullptr, N);
    agg2<1><<<blk1, 256, lds1, stream>>>(hwA, row_start, csr_src, dinv, gb2,
                                         nullptr, h_mlp, gateW, gateb,
                                         pW1, pb1, pW2, pb2, cW, cb,
                                         nullptr, logits, zproj, N);
}